// Round 1
// baseline (16629.008 us; speedup 1.0000x reference)
//
#include <hip/hip_runtime.h>
#include <math.h>

// Model: 8-layer transformer, B=16, S=512, H=1024, HEADS=4, dh=256, V=8000.
// Round 0: all-fp32 correctness anchor. No MFMA (CDNA4 has no fp32 MFMA);
// vector-ALU tiled GEMMs + flash-style attention.

#define NEGV (-1e30f)

// ---------------------------------------------------------------------------
// Embedding + sinusoidal PE:  z[b,s,c] = emb[x[b,s],c] + pe[s,c]
// ---------------------------------------------------------------------------
__global__ __launch_bounds__(256) void embed_kernel(
    const int* __restrict__ x, const float* __restrict__ emb,
    float* __restrict__ Z)
{
    const int tokidx = blockIdx.x;            // 0..8191 (b*512+s)
    const int s = tokidx & 511;
    const int t = threadIdx.x;
    const int tok = x[tokidx];
    const int c0 = t << 2;
    float4 e = *(const float4*)(emb + (size_t)tok * 1024 + c0);
    float pe[4];
#pragma unroll
    for (int j = 0; j < 4; ++j) {
        int c = c0 + j;
        float freq = expf((float)(c & ~1) * (-9.210340371976184f / 1024.f));
        float arg = (float)s * freq;
        pe[j] = (c & 1) ? cosf(arg) : sinf(arg);
    }
    float4 o = make_float4(e.x + pe[0], e.y + pe[1], e.z + pe[2], e.w + pe[3]);
    *(float4*)(Z + (size_t)tokidx * 1024 + c0) = o;
}

// ---------------------------------------------------------------------------
// NT GEMM: C[m,n] = sum_k A[m,k]*B[n,k] + bias[n]  (optional exact GELU)
// 64x64 block tile, 256 threads, 4x4 micro-tile, K-tile 16.
// M,N multiples of 64; K multiple of 16.
// ---------------------------------------------------------------------------
__global__ __launch_bounds__(256) void gemm_nt(
    const float* __restrict__ A, const float* __restrict__ B,
    const float* __restrict__ bias, float* __restrict__ C,
    int M, int N, int K, int gelu_flag)
{
    __shared__ __align__(16) float As[16][68];
    __shared__ __align__(16) float Bs[16][68];
    const int tid = threadIdx.x;
    const int m0 = blockIdx.y * 64;
    const int n0 = blockIdx.x * 64;
    const int srow = tid >> 2;          // 0..63
    const int sk = (tid & 3) << 2;      // 0,4,8,12
    const int tx = tid & 15;            // n micro
    const int ty = tid >> 4;            // m micro
    const float* Ap = A + (size_t)(m0 + srow) * K + sk;
    const float* Bp = B + (size_t)(n0 + srow) * K + sk;
    float acc[4][4] = {{0.f, 0.f, 0.f, 0.f}, {0.f, 0.f, 0.f, 0.f},
                       {0.f, 0.f, 0.f, 0.f}, {0.f, 0.f, 0.f, 0.f}};
    for (int k0 = 0; k0 < K; k0 += 16) {
        float4 av = *(const float4*)(Ap + k0);
        float4 bv = *(const float4*)(Bp + k0);
        __syncthreads();
        As[sk + 0][srow] = av.x; As[sk + 1][srow] = av.y;
        As[sk + 2][srow] = av.z; As[sk + 3][srow] = av.w;
        Bs[sk + 0][srow] = bv.x; Bs[sk + 1][srow] = bv.y;
        Bs[sk + 2][srow] = bv.z; Bs[sk + 3][srow] = bv.w;
        __syncthreads();
#pragma unroll
        for (int kk = 0; kk < 16; ++kk) {
            float4 a = *(const float4*)&As[kk][ty << 2];
            float4 b = *(const float4*)&Bs[kk][tx << 2];
            float ar[4] = {a.x, a.y, a.z, a.w};
            float br[4] = {b.x, b.y, b.z, b.w};
#pragma unroll
            for (int i = 0; i < 4; ++i)
#pragma unroll
                for (int j = 0; j < 4; ++j)
                    acc[i][j] += ar[i] * br[j];
        }
    }
#pragma unroll
    for (int i = 0; i < 4; ++i) {
        int m = m0 + (ty << 2) + i;
        float r[4];
#pragma unroll
        for (int j = 0; j < 4; ++j) {
            int n = n0 + (tx << 2) + j;
            float v = acc[i][j] + (bias ? bias[n] : 0.f);
            if (gelu_flag) v = 0.5f * v * (1.f + erff(v * 0.7071067811865475f));
            r[j] = v;
        }
        float4 st = make_float4(r[0], r[1], r[2], r[3]);
        *(float4*)(C + (size_t)m * N + n0 + (tx << 2)) = st;
    }
}

// ---------------------------------------------------------------------------
// Flash-style attention per (b, h, 8-query tile). Causal; query-only length
// mask; writes O in [B,HEADS,S,dh] flat order (faithful reshape bug) and
// atten=max_k p = 1/l on the last layer.
// ---------------------------------------------------------------------------
__global__ __launch_bounds__(256) void attn_kernel(
    const float* __restrict__ Q, const float* __restrict__ K,
    const float* __restrict__ V, const int* __restrict__ lengths,
    float* __restrict__ O, float* __restrict__ atten)
{
    __shared__ __align__(16) float Qs[8][260];
    __shared__ __align__(16) float KVs[32][260];
    __shared__ float Ss[8][32];
    __shared__ float mS[8], lS[8], aS[8];
    const int qt = blockIdx.x, h = blockIdx.y, b = blockIdx.z;
    const int q0 = qt * 8;
    const int tid = threadIdx.x;
    const int qq = tid >> 5;    // 0..7: query row in tile
    const int dg = tid & 31;    // lane group
    const int d0 = dg << 3;     // dim chunk base (8 dims/thread)
    const int len = lengths[b];

    {   // load Q tile
        const float* qp = Q + ((size_t)(b * 512 + q0 + qq) * 1024) + h * 256 + d0;
        *(float4*)&Qs[qq][d0]     = *(const float4*)qp;
        *(float4*)&Qs[qq][d0 + 4] = *(const float4*)(qp + 4);
    }
    if (tid < 8) { mS[tid] = -3.0e38f; lS[tid] = 0.f; aS[tid] = 0.f; }
    float oacc[8] = {0.f, 0.f, 0.f, 0.f, 0.f, 0.f, 0.f, 0.f};

    const int kmax = q0 + 8;    // causal upper bound for this tile
    for (int k0 = 0; k0 < kmax; k0 += 32) {
        const int kt = min(32, kmax - k0);
        __syncthreads();   // prev PV reads of KVs done; Qs/state visible (iter 0)
        for (int r = qq; r < kt; r += 8) {
            const float* kp = K + ((size_t)(b * 512 + k0 + r) * 1024) + h * 256 + d0;
            *(float4*)&KVs[r][d0]     = *(const float4*)kp;
            *(float4*)&KVs[r][d0 + 4] = *(const float4*)(kp + 4);
        }
        __syncthreads();
        // scores: thread (qq, dg) -> s[q0+qq, k0+dg]
        float s = NEGV;
        if (dg < kt && (k0 + dg) <= (q0 + qq)) {
            float a0 = 0.f;
#pragma unroll 8
            for (int c = 0; c < 64; ++c) {
                float4 qv = *(const float4*)&Qs[qq][c << 2];
                float4 kv = *(const float4*)&KVs[dg][c << 2];
                a0 += qv.x * kv.x + qv.y * kv.y + qv.z * kv.z + qv.w * kv.w;
            }
            s = a0 * 0.03125f;  // 1/sqrt(1024)
        }
        float smax = s;
#pragma unroll
        for (int off = 16; off; off >>= 1)
            smax = fmaxf(smax, __shfl_xor(smax, off, 32));
        float mold = mS[qq];                 // read-before-write within wave: safe
        float mnew = fmaxf(mold, smax);
        float p = expf(s - mnew);            // masked s -> 0
        float rsum = p;
#pragma unroll
        for (int off = 16; off; off >>= 1)
            rsum += __shfl_xor(rsum, off, 32);
        Ss[qq][dg] = p;
        if (dg == 0) {
            float alpha = expf(mold - mnew);
            lS[qq] = lS[qq] * alpha + rsum;
            mS[qq] = mnew;
            aS[qq] = alpha;
        }
        __syncthreads();                     // Ss/aS visible; K reads done
        float alpha = aS[qq];
#pragma unroll
        for (int j = 0; j < 8; ++j) oacc[j] *= alpha;
        for (int r = qq; r < kt; r += 8) {   // stage V over K
            const float* vp = V + ((size_t)(b * 512 + k0 + r) * 1024) + h * 256 + d0;
            *(float4*)&KVs[r][d0]     = *(const float4*)vp;
            *(float4*)&KVs[r][d0 + 4] = *(const float4*)(vp + 4);
        }
        __syncthreads();
        for (int kk = 0; kk < kt; ++kk) {
            float pk = Ss[qq][kk];
            float4 v1 = *(const float4*)&KVs[kk][d0];
            float4 v2 = *(const float4*)&KVs[kk][d0 + 4];
            oacc[0] += pk * v1.x; oacc[1] += pk * v1.y;
            oacc[2] += pk * v1.z; oacc[3] += pk * v1.w;
            oacc[4] += pk * v2.x; oacc[5] += pk * v2.y;
            oacc[6] += pk * v2.z; oacc[7] += pk * v2.w;
        }
    }
    __syncthreads();
    const bool valid = (q0 + qq) < len;
    const float linv = valid ? 1.f / lS[qq] : 0.f;
    float4 o1 = make_float4(oacc[0] * linv, oacc[1] * linv, oacc[2] * linv, oacc[3] * linv);
    float4 o2 = make_float4(oacc[4] * linv, oacc[5] * linv, oacc[6] * linv, oacc[7] * linv);
    // faithful reshape bug: write at [b][h][s][d] flat; consumed as [B,S,H]
    size_t obase = ((size_t)((b * 4 + h) * 512 + q0 + qq)) * 256 + d0;
    *(float4*)(O + obase)     = o1;
    *(float4*)(O + obase + 4) = o2;
    if (atten && dg == 0)
        atten[(size_t)(b * 4 + h) * 512 + q0 + qq] = linv;  // max_k p = 1/l
}

// ---------------------------------------------------------------------------
// Y[row] = LayerNorm(X[row] + R[row]) * g + be    (H = 1024)
// ---------------------------------------------------------------------------
__global__ __launch_bounds__(256) void add_ln(
    const float* __restrict__ X, const float* __restrict__ R,
    const float* __restrict__ g, const float* __restrict__ be,
    float* __restrict__ Y)
{
    __shared__ float red[8];
    const int row = blockIdx.x;
    const int t = threadIdx.x;
    const float4 x = ((const float4*)(X + (size_t)row * 1024))[t];
    const float4 r = ((const float4*)(R + (size_t)row * 1024))[t];
    float v[4] = {x.x + r.x, x.y + r.y, x.z + r.z, x.w + r.w};
    float s = v[0] + v[1] + v[2] + v[3];
#pragma unroll
    for (int off = 32; off; off >>= 1) s += __shfl_xor(s, off);
    const int wid = t >> 6;
    if ((t & 63) == 0) red[wid] = s;
    __syncthreads();
    s = red[0] + red[1] + red[2] + red[3];
    const float mean = s * (1.f / 1024.f);
    float q = 0.f;
#pragma unroll
    for (int j = 0; j < 4; ++j) { float d = v[j] - mean; q += d * d; }
#pragma unroll
    for (int off = 32; off; off >>= 1) q += __shfl_xor(q, off);
    if ((t & 63) == 0) red[4 + wid] = q;
    __syncthreads();
    q = red[4] + red[5] + red[6] + red[7];
    const float rstd = rsqrtf(q * (1.f / 1024.f) + 1e-5f);
    const float4 gv = ((const float4*)g)[t];
    const float4 bv = ((const float4*)be)[t];
    float4 o;
    o.x = (v[0] - mean) * rstd * gv.x + bv.x;
    o.y = (v[1] - mean) * rstd * gv.y + bv.y;
    o.z = (v[2] - mean) * rstd * gv.z + bv.z;
    o.w = (v[3] - mean) * rstd * gv.w + bv.w;
    ((float4*)(Y + (size_t)row * 1024))[t] = o;
}

// ---------------------------------------------------------------------------
// In-place row softmax over V=8000 (one block per row, values in registers)
// ---------------------------------------------------------------------------
__global__ __launch_bounds__(256) void softmax8000(float* __restrict__ P)
{
    __shared__ float red[8];
    float* p = P + (size_t)blockIdx.x * 8000;
    const int t = threadIdx.x;
    float vals[32];
    float mx = -3.0e38f;
#pragma unroll
    for (int j = 0; j < 32; ++j) {
        int c = t + (j << 8);
        if (c < 8000) { vals[j] = p[c]; mx = fmaxf(mx, vals[j]); }
    }
#pragma unroll
    for (int off = 32; off; off >>= 1) mx = fmaxf(mx, __shfl_xor(mx, off));
    const int wid = t >> 6;
    if ((t & 63) == 0) red[wid] = mx;
    __syncthreads();
    mx = fmaxf(fmaxf(red[0], red[1]), fmaxf(red[2], red[3]));
    float sum = 0.f;
#pragma unroll
    for (int j = 0; j < 32; ++j) {
        int c = t + (j << 8);
        if (c < 8000) { vals[j] = expf(vals[j] - mx); sum += vals[j]; }
    }
#pragma unroll
    for (int off = 32; off; off >>= 1) sum += __shfl_xor(sum, off);
    if ((t & 63) == 0) red[4 + wid] = sum;
    __syncthreads();
    const float inv = 1.f / (red[4] + red[5] + red[6] + red[7]);
#pragma unroll
    for (int j = 0; j < 32; ++j) {
        int c = t + (j << 8);
        if (c < 8000) p[c] = vals[j] * inv;
    }
}

// ---------------------------------------------------------------------------
extern "C" void kernel_launch(void* const* d_in, const int* in_sizes, int n_in,
                              void* d_out, int out_size, void* d_ws, size_t ws_size,
                              hipStream_t stream)
{
    (void)in_sizes; (void)n_in; (void)out_size;
    const int*   x       = (const int*)d_in[0];
    const int*   lengths = (const int*)d_in[1];
    const float* emb = (const float*)d_in[2];
    const float* Wq  = (const float*)d_in[3];
    const float* bq  = (const float*)d_in[4];
    const float* Wk  = (const float*)d_in[5];
    const float* bk  = (const float*)d_in[6];
    const float* Wv  = (const float*)d_in[7];
    const float* bv  = (const float*)d_in[8];
    const float* W1  = (const float*)d_in[9];
    const float* b1  = (const float*)d_in[10];
    const float* W2  = (const float*)d_in[11];
    const float* b2  = (const float*)d_in[12];
    const float* g1  = (const float*)d_in[13];
    const float* be1 = (const float*)d_in[14];
    const float* g2  = (const float*)d_in[15];
    const float* be2 = (const float*)d_in[16];
    const float* Wfc = (const float*)d_in[17];
    const float* bfc = (const float*)d_in[18];

    float* out = (float*)d_out;
    const size_t BUF = (size_t)8192 * 1024;
    float* wsf = (float*)d_ws;
    float *z, *z1, *qb, *kb, *vb, *ob, *fcb;
    if (ws_size >= 7 * BUF * sizeof(float)) {
        z = wsf;           z1 = wsf + BUF;    qb = wsf + 2 * BUF;
        kb = wsf + 3 * BUF; vb = wsf + 4 * BUF; ob = wsf + 5 * BUF;
        fcb = wsf + 6 * BUF;
    } else {
        // y_prim region of d_out (262 MB) is dead until the logits GEMM:
        // use its first 201 MB as scratch. out_fc must survive the logits
        // GEMM, so it lives in d_ws (33.5 MB needed).
        z = out;           z1 = out + BUF;    qb = out + 2 * BUF;
        kb = out + 3 * BUF; vb = out + 4 * BUF; ob = out + 5 * BUF;
        fcb = wsf;
    }
    float* atten = out + (size_t)65536000;

    dim3 blk(256);
    embed_kernel<<<8192, blk, 0, stream>>>(x, emb, z);
    for (int l = 0; l < 8; ++l) {
        const size_t WO = (size_t)l * 1024 * 1024;
        const size_t BO = (size_t)l * 1024;
        gemm_nt<<<dim3(16, 128), blk, 0, stream>>>(z,  Wq + WO, bq + BO, qb, 8192, 1024, 1024, 0);
        gemm_nt<<<dim3(16, 128), blk, 0, stream>>>(z,  Wk + WO, bk + BO, kb, 8192, 1024, 1024, 0);
        gemm_nt<<<dim3(16, 128), blk, 0, stream>>>(z,  Wv + WO, bv + BO, vb, 8192, 1024, 1024, 0);
        attn_kernel<<<dim3(64, 4, 16), blk, 0, stream>>>(qb, kb, vb, lengths, ob,
                                                         (l == 7) ? atten : nullptr);
        add_ln<<<8192, blk, 0, stream>>>(z, ob, g1 + BO, be1 + BO, z1);
        gemm_nt<<<dim3(16, 128), blk, 0, stream>>>(z1, W1 + WO, b1 + BO, qb, 8192, 1024, 1024, 1);
        gemm_nt<<<dim3(16, 128), blk, 0, stream>>>(qb, W2 + WO, b2 + BO, kb, 8192, 1024, 1024, 0);
        add_ln<<<8192, blk, 0, stream>>>(z1, kb, g2 + BO, be2 + BO, z);
    }
    gemm_nt<<<dim3(16, 128), blk, 0, stream>>>(z, Wfc, bfc, fcb, 8192, 1024, 1024, 0);
    gemm_nt<<<dim3(125, 128), blk, 0, stream>>>(fcb, emb, nullptr, out, 8192, 8000, 1024, 0);
    softmax8000<<<8192, blk, 0, stream>>>(out);
}

// Round 2
// 5982.693 us; speedup vs baseline: 2.7795x; 2.7795x over previous
//
#include <hip/hip_runtime.h>
#include <math.h>

// 8-layer transformer, B=16, S=512, H=1024, HEADS=4, dh=256, V=8000.
// Round 1: bf16 MFMA GEMMs (16x16x32, 128x128 tile, global_load_lds + XOR
// swizzle), fused QKV GEMM, bf16-LDS flash attention, dual fp32/bf16
// activation stream. fp32 residual/LN kept for accuracy.

typedef unsigned short u16;
typedef unsigned int u32;
typedef __attribute__((ext_vector_type(8))) short short8;
typedef __attribute__((ext_vector_type(4))) float f32x4;

__device__ __forceinline__ u16 f2bf(float f) {
    u32 u = __builtin_bit_cast(u32, f);
    u32 r = (u + 0x7FFFu + ((u >> 16) & 1u)) >> 16;
    return (u16)r;
}
__device__ __forceinline__ float bf2f(u16 u) {
    u32 v = ((u32)u) << 16;
    return __builtin_bit_cast(float, v);
}
__device__ __forceinline__ float4 unpack4(uint2 r) {
    float4 f;
    f.x = __builtin_bit_cast(float, r.x << 16);
    f.y = __builtin_bit_cast(float, r.x & 0xffff0000u);
    f.z = __builtin_bit_cast(float, r.y << 16);
    f.w = __builtin_bit_cast(float, r.y & 0xffff0000u);
    return f;
}

// async 16B/lane global->LDS; ldsbase must be wave-uniform (HW adds lane*16)
__device__ __forceinline__ void stage16(const void* g, void* ldsbase, int lane) {
#if __has_builtin(__builtin_amdgcn_global_load_lds)
    __builtin_amdgcn_global_load_lds(
        (const __attribute__((address_space(1))) u32*)g,
        (__attribute__((address_space(3))) u32*)ldsbase, 16, 0, 0);
#else
    *(short8*)((u16*)ldsbase + lane * 8) = *(const short8*)g;
#endif
}

// ---------------------------------------------------------------------------
// bf16 NT GEMM: C[m,n] = sum_k A[m,k]*B[n,k] + bias[n]
// flags: bit0 = bf16 output, bit1 = exact GELU. M%128==0, N%128==0, K%64==0.
// ---------------------------------------------------------------------------
__global__ __launch_bounds__(256) void gemm_bf16(
    const u16* __restrict__ A, const u16* __restrict__ B,
    const float* __restrict__ bias, void* __restrict__ C,
    int M, int N, int K, int ldc, int Nstore, int flags)
{
    __shared__ u16 As[128 * 64];
    __shared__ u16 Bs[128 * 64];
    const int tid = threadIdx.x;
    const int w = tid >> 6, lane = tid & 63;
    const int m0 = blockIdx.y * 128, n0 = blockIdx.x * 128;
    const int lr = lane >> 3;      // staging row-in-group
    const int lc = lane & 7;       // staging chunk slot
    f32x4 acc[4][4];
#pragma unroll
    for (int i = 0; i < 4; ++i)
#pragma unroll
        for (int j = 0; j < 4; ++j) {
            acc[i][j][0] = 0.f; acc[i][j][1] = 0.f;
            acc[i][j][2] = 0.f; acc[i][j][3] = 0.f;
        }
    const int row = lane & 15, quad = lane >> 4;
    const int wm = (w >> 1) * 64, wn = (w & 1) * 64;

    for (int k0 = 0; k0 < K; k0 += 64) {
        __syncthreads();                       // prev MFMA reads complete
#pragma unroll
        for (int i = 0; i < 4; ++i) {
            const int ra = (w * 4 + i) * 8 + lr;         // tile row 0..127
            const int ca = lc ^ (ra & 7);                // swizzled global chunk
            stage16(A + (size_t)(m0 + ra) * K + k0 + ca * 8, &As[(w * 4 + i) * 512], lane);
            stage16(B + (size_t)(n0 + ra) * K + k0 + ca * 8, &Bs[(w * 4 + i) * 512], lane);
        }
        __syncthreads();                       // staging drained (vmcnt before barrier)
#pragma unroll
        for (int kk = 0; kk < 2; ++kk) {
            const int g0 = kk * 4 + quad;      // global 8-elem chunk index
            short8 af[4], bfr[4];
#pragma unroll
            for (int i = 0; i < 4; ++i) {
                const int r = wm + i * 16 + row;
                af[i] = *(const short8*)&As[r * 64 + ((g0 ^ (r & 7)) * 8)];
            }
#pragma unroll
            for (int j = 0; j < 4; ++j) {
                const int r = wn + j * 16 + row;
                bfr[j] = *(const short8*)&Bs[r * 64 + ((g0 ^ (r & 7)) * 8)];
            }
#pragma unroll
            for (int i = 0; i < 4; ++i)
#pragma unroll
                for (int j = 0; j < 4; ++j)
                    acc[i][j] = __builtin_amdgcn_mfma_f32_16x16x32_bf16(
                        af[i], bfr[j], acc[i][j], 0, 0, 0);
        }
    }
    // epilogue: D[row=(lane>>4)*4+r][col=lane&15] per 16x16 tile
    const int do_bf = flags & 1, do_gelu = flags & 2;
#pragma unroll
    for (int i = 0; i < 4; ++i)
#pragma unroll
        for (int j = 0; j < 4; ++j) {
            const int gr0 = m0 + wm + i * 16 + quad * 4;
            const int gc = n0 + wn + j * 16 + row;
            if (gc < Nstore) {
                const float bv = bias ? bias[gc] : 0.f;
#pragma unroll
                for (int r = 0; r < 4; ++r) {
                    float v = acc[i][j][r] + bv;
                    if (do_gelu) v = 0.5f * v * (1.f + erff(v * 0.7071067811865475f));
                    if (do_bf) ((u16*)C)[(size_t)(gr0 + r) * ldc + gc] = f2bf(v);
                    else       ((float*)C)[(size_t)(gr0 + r) * ldc + gc] = v;
                }
            }
        }
}

// ---------------------------------------------------------------------------
// Flash attention, bf16 LDS. Grid (16 qtiles, 4 heads, 16 batch), 256 thr.
// QKV rows [8192][3072]: q=cols h*256.., k=1024+h*256.., v=2048+h*256..
// Writes O fp32 in faithful [B,HEADS,S,dh] flat order; atten=1/l (layer 7).
// ---------------------------------------------------------------------------
__global__ __launch_bounds__(256) void attn_bf16(
    const u16* __restrict__ QKV, const int* __restrict__ lengths,
    float* __restrict__ O, float* __restrict__ atten)
{
    __shared__ u16 Qs[32][264];
    __shared__ u16 KVs[32][264];
    __shared__ float Ss[32][36];
    const int qt = blockIdx.x, h = blockIdx.y, b = blockIdx.z;
    const int q0 = qt * 32;
    const int t = threadIdx.x;
    const int qi = t >> 3, s = t & 7;
    const int qg = q0 + qi;
    const int len = lengths[b];

    {   // stage Q tile (row qi, strided 4-elem chunks -> conflict-free)
        const u16* qp = QKV + (size_t)(b * 512 + qg) * 3072 + h * 256;
#pragma unroll
        for (int jj = 0; jj < 8; ++jj) {
            const int c = s * 4 + 32 * jj;
            *(ushort4*)&Qs[qi][c] = *(const ushort4*)(qp + c);
        }
    }
    float m = -3.0e38f, l = 0.f;
    float4 o[8];
#pragma unroll
    for (int jj = 0; jj < 8; ++jj) o[jj] = make_float4(0.f, 0.f, 0.f, 0.f);

    for (int kt = 0; kt <= qt; ++kt) {
        const int k0 = kt * 32;
        __syncthreads();                       // prev PV reads done; Qs visible
        {   // stage K
            const u16* kp = QKV + (size_t)(b * 512 + k0 + qi) * 3072 + 1024 + h * 256;
#pragma unroll
            for (int jj = 0; jj < 8; ++jj) {
                const int c = s * 4 + 32 * jj;
                *(ushort4*)&KVs[qi][c] = *(const ushort4*)(kp + c);
            }
        }
        __syncthreads();
        // scores: thread (qi, s) -> keys k = s + 8j
        float a0 = 0.f, a1 = 0.f, a2 = 0.f, a3 = 0.f;
#pragma unroll 4
        for (int dc = 0; dc < 64; ++dc) {
            const float4 qv = unpack4(*(const uint2*)&Qs[qi][dc * 4]);
            float4 kv;
            kv = unpack4(*(const uint2*)&KVs[s][dc * 4]);
            a0 += qv.x * kv.x + qv.y * kv.y + qv.z * kv.z + qv.w * kv.w;
            kv = unpack4(*(const uint2*)&KVs[s + 8][dc * 4]);
            a1 += qv.x * kv.x + qv.y * kv.y + qv.z * kv.z + qv.w * kv.w;
            kv = unpack4(*(const uint2*)&KVs[s + 16][dc * 4]);
            a2 += qv.x * kv.x + qv.y * kv.y + qv.z * kv.z + qv.w * kv.w;
            kv = unpack4(*(const uint2*)&KVs[s + 24][dc * 4]);
            a3 += qv.x * kv.x + qv.y * kv.y + qv.z * kv.z + qv.w * kv.w;
        }
        float sc[4] = {a0, a1, a2, a3};
#pragma unroll
        for (int j = 0; j < 4; ++j) {
            const int kg = k0 + s + 8 * j;
            sc[j] = (kg <= qg) ? sc[j] * 0.03125f : -3.0e38f;   // 1/sqrt(1024)
        }
        float lm = fmaxf(fmaxf(sc[0], sc[1]), fmaxf(sc[2], sc[3]));
        lm = fmaxf(lm, __shfl_xor(lm, 1));
        lm = fmaxf(lm, __shfl_xor(lm, 2));
        lm = fmaxf(lm, __shfl_xor(lm, 4));
        const float mnew = fmaxf(m, lm);
        const float alpha = expf(m - mnew);    // first tile: exp(-inf) = 0
        float p[4], ps = 0.f;
#pragma unroll
        for (int j = 0; j < 4; ++j) { p[j] = expf(sc[j] - mnew); ps += p[j]; }
        ps += __shfl_xor(ps, 1);
        ps += __shfl_xor(ps, 2);
        ps += __shfl_xor(ps, 4);
        l = l * alpha + ps;
        m = mnew;
#pragma unroll
        for (int j = 0; j < 4; ++j) Ss[qi][s + 8 * j] = p[j];
#pragma unroll
        for (int jj = 0; jj < 8; ++jj) {
            o[jj].x *= alpha; o[jj].y *= alpha; o[jj].z *= alpha; o[jj].w *= alpha;
        }
        __syncthreads();                       // score reads of KVs done; Ss visible
        {   // stage V over K
            const u16* vp = QKV + (size_t)(b * 512 + k0 + qi) * 3072 + 2048 + h * 256;
#pragma unroll
            for (int jj = 0; jj < 8; ++jj) {
                const int c = s * 4 + 32 * jj;
                *(ushort4*)&KVs[qi][c] = *(const ushort4*)(vp + c);
            }
        }
        __syncthreads();
        for (int kk = 0; kk < 32; ++kk) {
            const float pk = Ss[qi][kk];
#pragma unroll
            for (int jj = 0; jj < 8; ++jj) {
                const float4 vv = unpack4(*(const uint2*)&KVs[kk][s * 4 + 32 * jj]);
                o[jj].x += pk * vv.x; o[jj].y += pk * vv.y;
                o[jj].z += pk * vv.z; o[jj].w += pk * vv.w;
            }
        }
    }
    const float linv = (qg < len) ? 1.f / l : 0.f;
    float* op = O + ((size_t)((b * 4 + h) * 512 + qg)) * 256;   // faithful reshape bug
#pragma unroll
    for (int jj = 0; jj < 8; ++jj) {
        const float4 ov = make_float4(o[jj].x * linv, o[jj].y * linv,
                                      o[jj].z * linv, o[jj].w * linv);
        *(float4*)(op + s * 4 + 32 * jj) = ov;
    }
    if (atten && s == 0)
        atten[(size_t)(b * 4 + h) * 512 + qg] = linv;           // max_k p = 1/l
}

// ---------------------------------------------------------------------------
// Embedding + sinusoidal PE, dual fp32/bf16 output
// ---------------------------------------------------------------------------
__global__ __launch_bounds__(256) void embed_kernel(
    const int* __restrict__ x, const float* __restrict__ emb,
    float* __restrict__ Z, u16* __restrict__ Zb)
{
    const int tokidx = blockIdx.x;
    const int s = tokidx & 511;
    const int t = threadIdx.x;
    const int tok = x[tokidx];
    const int c0 = t << 2;
    float4 e = *(const float4*)(emb + (size_t)tok * 1024 + c0);
    float pe[4];
#pragma unroll
    for (int j = 0; j < 4; ++j) {
        int c = c0 + j;
        float freq = expf((float)(c & ~1) * (-9.210340371976184f / 1024.f));
        float arg = (float)s * freq;
        pe[j] = (c & 1) ? cosf(arg) : sinf(arg);
    }
    float4 o = make_float4(e.x + pe[0], e.y + pe[1], e.z + pe[2], e.w + pe[3]);
    *(float4*)(Z + (size_t)tokidx * 1024 + c0) = o;
    ushort4 ob = {f2bf(o.x), f2bf(o.y), f2bf(o.z), f2bf(o.w)};
    ((ushort4*)(Zb + (size_t)tokidx * 1024))[t] = ob;
}

// ---------------------------------------------------------------------------
// Y = LayerNorm(X + R) * g + be, dual fp32/bf16 output (H = 1024)
// ---------------------------------------------------------------------------
__global__ __launch_bounds__(256) void add_ln(
    const float* __restrict__ X, const float* __restrict__ R,
    const float* __restrict__ g, const float* __restrict__ be,
    float* __restrict__ Y, u16* __restrict__ Yb)
{
    __shared__ float red[8];
    const int row = blockIdx.x;
    const int t = threadIdx.x;
    const float4 x = ((const float4*)(X + (size_t)row * 1024))[t];
    const float4 r = ((const float4*)(R + (size_t)row * 1024))[t];
    float v[4] = {x.x + r.x, x.y + r.y, x.z + r.z, x.w + r.w};
    float s = v[0] + v[1] + v[2] + v[3];
#pragma unroll
    for (int off = 32; off; off >>= 1) s += __shfl_xor(s, off);
    const int wid = t >> 6;
    if ((t & 63) == 0) red[wid] = s;
    __syncthreads();
    s = red[0] + red[1] + red[2] + red[3];
    const float mean = s * (1.f / 1024.f);
    float q = 0.f;
#pragma unroll
    for (int j = 0; j < 4; ++j) { float d = v[j] - mean; q += d * d; }
#pragma unroll
    for (int off = 32; off; off >>= 1) q += __shfl_xor(q, off);
    if ((t & 63) == 0) red[4 + wid] = q;
    __syncthreads();
    q = red[4] + red[5] + red[6] + red[7];
    const float rstd = rsqrtf(q * (1.f / 1024.f) + 1e-5f);
    const float4 gv = ((const float4*)g)[t];
    const float4 bv = ((const float4*)be)[t];
    float4 o;
    o.x = (v[0] - mean) * rstd * gv.x + bv.x;
    o.y = (v[1] - mean) * rstd * gv.y + bv.y;
    o.z = (v[2] - mean) * rstd * gv.z + bv.z;
    o.w = (v[3] - mean) * rstd * gv.w + bv.w;
    ((float4*)(Y + (size_t)row * 1024))[t] = o;
    ushort4 ob = {f2bf(o.x), f2bf(o.y), f2bf(o.z), f2bf(o.w)};
    ((ushort4*)(Yb + (size_t)row * 1024))[t] = ob;
}

// ---------------------------------------------------------------------------
// In-place row softmax over V=8000
// ---------------------------------------------------------------------------
__global__ __launch_bounds__(256) void softmax8000(float* __restrict__ P)
{
    __shared__ float red[8];
    float* p = P + (size_t)blockIdx.x * 8000;
    const int t = threadIdx.x;
    float vals[32];
    float mx = -3.0e38f;
#pragma unroll
    for (int j = 0; j < 32; ++j) {
        int c = t + (j << 8);
        if (c < 8000) { vals[j] = p[c]; mx = fmaxf(mx, vals[j]); }
    }
#pragma unroll
    for (int off = 32; off; off >>= 1) mx = fmaxf(mx, __shfl_xor(mx, off));
    const int wid = t >> 6;
    if ((t & 63) == 0) red[wid] = mx;
    __syncthreads();
    mx = fmaxf(fmaxf(red[0], red[1]), fmaxf(red[2], red[3]));
    float sum = 0.f;
#pragma unroll
    for (int j = 0; j < 32; ++j) {
        int c = t + (j << 8);
        if (c < 8000) { vals[j] = expf(vals[j] - mx); sum += vals[j]; }
    }
#pragma unroll
    for (int off = 32; off; off >>= 1) sum += __shfl_xor(sum, off);
    if ((t & 63) == 0) red[4 + wid] = sum;
    __syncthreads();
    const float inv = 1.f / (red[4] + red[5] + red[6] + red[7]);
#pragma unroll
    for (int j = 0; j < 32; ++j) {
        int c = t + (j << 8);
        if (c < 8000) p[c] = vals[j] * inv;
    }
}

// ---------------------------------------------------------------------------
// Weight / embedding conversion kernels (fp32 -> bf16), run each call
// ---------------------------------------------------------------------------
__global__ __launch_bounds__(256) void cvt_qkv(
    const float* __restrict__ Wq, const float* __restrict__ Wk,
    const float* __restrict__ Wv, u16* __restrict__ dst)
{
    const int n = blockIdx.x, l = blockIdx.y, t = threadIdx.x;
    const float* src = (n < 1024) ? Wq + ((size_t)l * 1024 + n) * 1024
                     : (n < 2048) ? Wk + ((size_t)l * 1024 + (n - 1024)) * 1024
                                  : Wv + ((size_t)l * 1024 + (n - 2048)) * 1024;
    float4 v = ((const float4*)src)[t];
    ushort4 o = {f2bf(v.x), f2bf(v.y), f2bf(v.z), f2bf(v.w)};
    ((ushort4*)(dst + ((size_t)l * 3072 + n) * 1024))[t] = o;
}

__global__ __launch_bounds__(256) void cvt_bias_qkv(
    const float* __restrict__ bq, const float* __restrict__ bk,
    const float* __restrict__ bv, float* __restrict__ dst)
{
    const int i = blockIdx.x * 256 + threadIdx.x;
    if (i >= 8 * 3072) return;
    const int l = i / 3072, n = i - l * 3072;
    float v = (n < 1024) ? bq[l * 1024 + n]
            : (n < 2048) ? bk[l * 1024 + (n - 1024)]
                         : bv[l * 1024 + (n - 2048)];
    dst[i] = v;
}

__global__ __launch_bounds__(256) void cvt_plain(
    const float* __restrict__ src, u16* __restrict__ dst, int n)
{
    const int i = (blockIdx.x * 256 + threadIdx.x) * 4;
    if (i >= n) return;
    float4 v = *(const float4*)(src + i);
    ushort4 o = {f2bf(v.x), f2bf(v.y), f2bf(v.z), f2bf(v.w)};
    *(ushort4*)(dst + i) = o;
}

__global__ __launch_bounds__(256) void cvt_emb(
    const float* __restrict__ emb, u16* __restrict__ dst)
{
    const int r = blockIdx.x, t = threadIdx.x;   // 8064 rows (pad to tile)
    ushort4 o = {0, 0, 0, 0};
    if (r < 8000) {
        float4 v = ((const float4*)(emb + (size_t)r * 1024))[t];
        o.x = f2bf(v.x); o.y = f2bf(v.y); o.z = f2bf(v.z); o.w = f2bf(v.w);
    }
    ((ushort4*)(dst + (size_t)r * 1024))[t] = o;
}

// ---------------------------------------------------------------------------
extern "C" void kernel_launch(void* const* d_in, const int* in_sizes, int n_in,
                              void* d_out, int out_size, void* d_ws, size_t ws_size,
                              hipStream_t stream)
{
    (void)in_sizes; (void)n_in; (void)out_size;
    const int*   x       = (const int*)d_in[0];
    const int*   lengths = (const int*)d_in[1];
    const float* emb = (const float*)d_in[2];
    const float* Wq  = (const float*)d_in[3];
    const float* bq  = (const float*)d_in[4];
    const float* Wk  = (const float*)d_in[5];
    const float* bk  = (const float*)d_in[6];
    const float* Wv  = (const float*)d_in[7];
    const float* bv  = (const float*)d_in[8];
    const float* W1  = (const float*)d_in[9];
    const float* b1  = (const float*)d_in[10];
    const float* W2  = (const float*)d_in[11];
    const float* b2  = (const float*)d_in[12];
    const float* g1  = (const float*)d_in[13];
    const float* be1 = (const float*)d_in[14];
    const float* g2  = (const float*)d_in[15];
    const float* be2 = (const float*)d_in[16];
    const float* Wfc = (const float*)d_in[17];
    const float* bfc = (const float*)d_in[18];

    float* out = (float*)d_out;
    float* atten = out + (size_t)65536000;

    // ---- buffer sizes (bytes, all 256-aligned already) ----
    const size_t SZ_EMBB = (size_t)8064 * 1024 * 2;   // padded emb bf16
    const size_t SZ_FCB  = (size_t)8192 * 1024 * 2;   // out_fc bf16 (survives to logits)
    const size_t SZ_BQKV = (size_t)8 * 3072 * 4;
    const size_t SZ_WQKV = (size_t)8 * 3072 * 1024 * 2;
    const size_t SZ_W12  = (size_t)8 * 1024 * 1024 * 2;
    const size_t SZ_WFC  = (size_t)1024 * 1024 * 2;
    const size_t SZ_Z    = (size_t)8192 * 1024 * 4;
    const size_t SZ_ZB   = (size_t)8192 * 1024 * 2;
    const size_t SZ_QKVB = (size_t)8192 * 3072 * 2;
    const size_t NONFORCED = SZ_WQKV + 2 * SZ_W12 + SZ_WFC + 2 * SZ_Z + SZ_ZB + SZ_QKVB + SZ_Z;
    const size_t FORCED = SZ_EMBB + SZ_FCB + SZ_BQKV;
    const size_t GRAND = FORCED + NONFORCED;

    char* wsc = (char*)d_ws;
    char* oc  = (char*)d_out;
    const size_t ocap = (size_t)65536000 * 4;   // y_prim region: dead until logits GEMM
    size_t wo = 0, oo = 0;
    const bool all_ws = ws_size >= GRAND;
    // forced-to-ws (must survive while logits GEMM overwrites d_out):
    u16*   emb_bf = (u16*)(wsc + wo);  wo += SZ_EMBB;
    u16*   fc_b   = (u16*)(wsc + wo);  wo += SZ_FCB;
    float* bqkv   = (float*)(wsc + wo); wo += SZ_BQKV;
    auto alloc = [&](size_t sz) -> char* {
        if (all_ws) { char* p = wsc + wo; wo += sz; return p; }
        if (oo + sz <= ocap) { char* p = oc + oo; oo += sz; return p; }
        char* p = wsc + wo; wo += sz; return p;
    };
    u16*   Wqkv_bf = (u16*)alloc(SZ_WQKV);
    u16*   W1b     = (u16*)alloc(SZ_W12);
    u16*   W2b     = (u16*)alloc(SZ_W12);
    u16*   Wfcb    = (u16*)alloc(SZ_WFC);
    float* z       = (float*)alloc(SZ_Z);
    float* z1      = (float*)alloc(SZ_Z);
    u16*   zb      = (u16*)alloc(SZ_ZB);
    u16*   qkvb    = (u16*)alloc(SZ_QKVB);
    float* o       = (float*)alloc(SZ_Z);
    // aliases inside qkvb (attention finishes before these are written):
    u16* z1b = qkvb;                            // [8192][1024] bf16
    u16* f1b = qkvb + (size_t)8192 * 1024;      // [8192][1024] bf16

    dim3 blk(256);
    // weight / emb conversion (reads pristine fp32 inputs every call)
    cvt_qkv<<<dim3(3072, 8), blk, 0, stream>>>(Wq, Wk, Wv, Wqkv_bf);
    cvt_bias_qkv<<<96, blk, 0, stream>>>(bq, bk, bv, bqkv);
    cvt_plain<<<8192, blk, 0, stream>>>(W1, W1b, 8 * 1024 * 1024);
    cvt_plain<<<8192, blk, 0, stream>>>(W2, W2b, 8 * 1024 * 1024);
    cvt_plain<<<1024, blk, 0, stream>>>(Wfc, Wfcb, 1024 * 1024);
    cvt_emb<<<8064, blk, 0, stream>>>(emb, emb_bf);

    embed_kernel<<<8192, blk, 0, stream>>>(x, emb, z, zb);

    for (int l = 0; l < 8; ++l) {
        const size_t WO1 = (size_t)l * 1024 * 1024;
        const size_t BO = (size_t)l * 1024;
        // fused QKV GEMM: [8192,3072] bf16 out
        gemm_bf16<<<dim3(24, 64), blk, 0, stream>>>(
            zb, Wqkv_bf + (size_t)l * 3072 * 1024, bqkv + (size_t)l * 3072,
            qkvb, 8192, 3072, 1024, 3072, 3072, 1);
        attn_bf16<<<dim3(16, 4, 16), blk, 0, stream>>>(
            qkvb, lengths, o, (l == 7) ? atten : nullptr);
        add_ln<<<8192, blk, 0, stream>>>(z, o, g1 + BO, be1 + BO, z1, z1b);
        gemm_bf16<<<dim3(8, 64), blk, 0, stream>>>(
            z1b, W1b + WO1, b1 + BO, f1b, 8192, 1024, 1024, 1024, 1024, 1 | 2);
        gemm_bf16<<<dim3(8, 64), blk, 0, stream>>>(
            f1b, W2b + WO1, b2 + BO, o, 8192, 1024, 1024, 1024, 1024, 0);
        add_ln<<<8192, blk, 0, stream>>>(z1, o, g2 + BO, be2 + BO, z, zb);
    }
    gemm_bf16<<<dim3(8, 64), blk, 0, stream>>>(
        zb, Wfcb, bfc, fc_b, 8192, 1024, 1024, 1024, 1024, 1);
    gemm_bf16<<<dim3(63, 64), blk, 0, stream>>>(
        fc_b, emb_bf, nullptr, out, 8192, 8064, 1024, 8000, 8000, 0);
    softmax8000<<<8192, blk, 0, stream>>>(out);
}